// Round 8
// baseline (615.730 us; speedup 1.0000x reference)
//
#include <hip/hip_runtime.h>

// RES=[64,128,256,512,1024], NF=8, NC=2, P=1e6. out[p*40 + lvl*8 + c], fp32.
//
// Pipeline (fused, deterministic output):
//  memset(hist)
//  K1: absmax partials (blocks [0,5456)) || point histogram (blocks [5456,7504))
//  K2: reduce scales + exclusive scan of 16384 Morton buckets (1 block)
//  K3: int8 quantize (blocks [0,10912)) || sort-scatter (blocks [10912,12960))
//      scatter emits ONE 16B slot {xn, yn, perm, 0} per point
//  K4: sample 2 sorted points/thread, depth-2 level pipeline; wave lanes are
//      spatial neighbors -> gathers L1/L2-hit; output stores non-temporal so
//      the 160MB out-stream doesn't evict hot table lines from L2.
//
// d_ws layout (bytes):
//   deq[8] f32        @ 0
//   inv[8] f32        @ 32
//   partials[5456]    @ 64
//   hist[16384]       @ 24576
//   starts[16384]     @ 90112
//   cursor[16384]     @ 155648
//   slots[P] 16B      @ 262144    ({xn,yn,perm,pad})
//   tables (uint2/px) @ 17301504

#define WS_PART 64
#define WS_HIST 24576
#define WS_START 90112
#define WS_CURS 155648
#define WS_SLOT 262144
#define WS_TAB 17301504
#define NBUCK 16384

typedef float __attribute__((ext_vector_type(4))) f32x4;

__device__ __forceinline__ unsigned part1by1(unsigned v) {
  v &= 0x0000FFFFu;
  v = (v | (v << 8)) & 0x00FF00FFu;
  v = (v | (v << 4)) & 0x0F0F0F0Fu;
  v = (v | (v << 2)) & 0x33333333u;
  v = (v | (v << 1)) & 0x55555555u;
  return v;
}

__device__ __forceinline__ int bucket_of(float xv, float yv) {
  int bx = (int)(xv * 128.0f);
  int by = (int)(yv * 128.0f);
  bx = min(max(bx, 0), 127);
  by = min(max(by, 0), 127);
  return (int)(part1by1((unsigned)bx) | (part1by1((unsigned)by) << 1));
}

// ---- K1: absmax partials || histogram ----
__global__ __launch_bounds__(256) void absmax_hist_kernel(
    const float* __restrict__ s0, const float* __restrict__ s1,
    const float* __restrict__ s2, const float* __restrict__ s3,
    const float* __restrict__ s4, unsigned* __restrict__ partials,
    const float* __restrict__ x, const float* __restrict__ y, int P,
    unsigned* __restrict__ hist) {
  int b = blockIdx.x;
  if (b >= 5456) {  // histogram part
    int nb = gridDim.x - 5456;
    int stride = nb * 256;
    for (int p = (b - 5456) * 256 + (int)threadIdx.x; p < P; p += stride)
      atomicAdd(&hist[bucket_of(x[p], y[p])], 1u);
    return;
  }
  __shared__ unsigned red[4];
  const float* src; int n4; int lb; int nb;
  if (b < 16)        { src = s0; n4 = 16384;   lb = 0;    nb = 16; }
  else if (b < 80)   { src = s1; n4 = 65536;   lb = 16;   nb = 64; }
  else if (b < 336)  { src = s2; n4 = 262144;  lb = 80;   nb = 256; }
  else if (b < 1360) { src = s3; n4 = 1048576; lb = 336;  nb = 1024; }
  else               { src = s4; n4 = 4194304; lb = 1360; nb = 4096; }
  int local = b - lb;
  unsigned m = 0;
  for (int k = local * 256 + threadIdx.x; k < n4; k += nb * 256) {
    f32x4 v = __builtin_nontemporal_load(&((const f32x4*)src)[k]);
    unsigned a = __float_as_uint(v.x) & 0x7FFFFFFFu;
    unsigned c = __float_as_uint(v.y) & 0x7FFFFFFFu;
    unsigned d = __float_as_uint(v.z) & 0x7FFFFFFFu;
    unsigned e = __float_as_uint(v.w) & 0x7FFFFFFFu;
    m = max(m, max(max(a, c), max(d, e)));
  }
#pragma unroll
  for (int off = 32; off; off >>= 1)
    m = max(m, (unsigned)__shfl_xor((int)m, off));
  if ((threadIdx.x & 63) == 0) red[threadIdx.x >> 6] = m;
  __syncthreads();
  if (threadIdx.x == 0)
    partials[b] = max(max(red[0], red[1]), max(red[2], red[3]));
}

// ---- K2: reduce scales + scan (one block, 256 threads) ----
__global__ __launch_bounds__(256) void scales_scan_kernel(
    const unsigned* __restrict__ partials, float* __restrict__ deq,
    float* __restrict__ inv, const unsigned* __restrict__ hist,
    unsigned* __restrict__ starts, unsigned* __restrict__ cursor) {
  __shared__ unsigned red[4];
  __shared__ unsigned sums[256];
  int t = (int)threadIdx.x;
  const int lo[5] = {0, 16, 80, 336, 1360};
  const int hi[5] = {16, 80, 336, 1360, 5456};
  for (int l = 0; l < 5; ++l) {
    unsigned m = 0;
    for (int i = lo[l] + t; i < hi[l]; i += 256) m = max(m, partials[i]);
#pragma unroll
    for (int off = 32; off; off >>= 1)
      m = max(m, (unsigned)__shfl_xor((int)m, off));
    if ((t & 63) == 0) red[t >> 6] = m;
    __syncthreads();
    if (t == 0) {
      unsigned r = max(max(red[0], red[1]), max(red[2], red[3]));
      float s = __uint_as_float(r);
      if (!(s > 0.0f)) s = 1e-20f;
      deq[l] = s / 127.0f;
      inv[l] = 127.0f / s;
    }
    __syncthreads();
  }
  unsigned local[64];
  unsigned s = 0;
#pragma unroll
  for (int i = 0; i < 64; ++i) { local[i] = s; s += hist[t * 64 + i]; }
  sums[t] = s;
  __syncthreads();
  for (int off = 1; off < 256; off <<= 1) {
    unsigned v = (t >= off) ? sums[t - off] : 0u;
    __syncthreads();
    sums[t] += v;
    __syncthreads();
  }
  unsigned base = (t == 0) ? 0u : sums[t - 1];
#pragma unroll
  for (int i = 0; i < 64; ++i) {
    unsigned v = base + local[i];
    starts[t * 64 + i] = v;
    cursor[t * 64 + i] = v;
  }
}

// ---- K3: quantize || scatter ----
__global__ __launch_bounds__(256) void quant_scatter_kernel(
    const float* __restrict__ s0, const float* __restrict__ s1,
    const float* __restrict__ s2, const float* __restrict__ s3,
    const float* __restrict__ s4, uint2* __restrict__ tb,
    const float* __restrict__ invp,
    const float* __restrict__ x, const float* __restrict__ y, int P,
    unsigned* __restrict__ cursor, f32x4* __restrict__ slots) {
  int b = blockIdx.x;
  if (b >= 10912) {  // scatter part
    int nb = gridDim.x - 10912;
    int stride = nb * 256;
    for (int p = (b - 10912) * 256 + (int)threadIdx.x; p < P; p += stride) {
      float xv = x[p], yv = y[p];
      int bk = bucket_of(xv, yv);
      unsigned slot = atomicAdd(&cursor[bk], 1u);
      f32x4 s;
      s.x = xv * 2.0f - 1.0f;
      s.y = yv * 2.0f - 1.0f;
      s.z = __int_as_float(p);
      s.w = 0.0f;
      slots[slot] = s;
    }
    return;
  }
  const float* src; int HW; int lb; int l; size_t toff;
  if (b < 32)        { src = s0; HW = 4096;    lb = 0;    l = 0; toff = 0; }
  else if (b < 160)  { src = s1; HW = 16384;   lb = 32;   l = 1; toff = 8192; }
  else if (b < 672)  { src = s2; HW = 65536;   lb = 160;  l = 2; toff = 40960; }
  else if (b < 2720) { src = s3; HW = 262144;  lb = 672;  l = 3; toff = 172032; }
  else               { src = s4; HW = 1048576; lb = 2720; l = 4; toff = 696320; }
  int i = (b - lb) * 256 + (int)threadIdx.x;
  float sc = invp[l];
  int cell = i / HW;
  int pix = i - cell * HW;
  const float* s = src + (size_t)cell * 8u * (size_t)HW + (size_t)pix;
  unsigned lov = 0, hiv = 0;
#pragma unroll
  for (int c = 0; c < 4; ++c) {
    int q = (int)rintf(s[(size_t)c * HW] * sc);
    q = min(max(q, -127), 127);
    lov |= ((unsigned)(q & 0xFF)) << (8 * c);
  }
#pragma unroll
  for (int c = 0; c < 4; ++c) {
    int q = (int)rintf(s[(size_t)(c + 4) * HW] * sc);
    q = min(max(q, -127), 127);
    hiv |= ((unsigned)(q & 0xFF)) << (8 * c);
  }
  tb[toff + (size_t)i] = make_uint2(lov, hiv);
}

// ---- sampling ----
template <int W>
__device__ __forceinline__ void level_idx(float xn, float yn, int* __restrict__ idx) {
#pragma unroll
  for (int cell = 0; cell < 2; ++cell) {
    const float off = 0.5f * (float)cell;
    float ix = (xn + 1.0f) * 0.5f * (float)(W - 1) + off;
    float iy = (yn + 1.0f) * 0.5f * (float)(W - 1) + off;
    int xi = (int)floorf(ix);
    int yi = (int)floorf(iy);
    xi = min(max(xi, 0), W - 1);
    yi = min(max(yi, 0), W - 1);
    int xb = min(xi + 1, W - 1);
    int yb = min(yi + 1, W - 1);
    int base = cell * W * W;
    idx[cell * 4 + 0] = base + yi * W + xi;
    idx[cell * 4 + 1] = base + yi * W + xb;
    idx[cell * 4 + 2] = base + yb * W + xi;
    idx[cell * 4 + 3] = base + yb * W + xb;
  }
}

template <int W>
__device__ __forceinline__ void level_weights(float xn, float yn, float* __restrict__ wgt) {
#pragma unroll
  for (int cell = 0; cell < 2; ++cell) {
    const float off = 0.5f * (float)cell;
    float ix = (xn + 1.0f) * 0.5f * (float)(W - 1) + off;
    float iy = (yn + 1.0f) * 0.5f * (float)(W - 1) + off;
    float wx = ix - floorf(ix);
    float wy = iy - floorf(iy);
    wgt[cell * 4 + 0] = (1.0f - wx) * (1.0f - wy);
    wgt[cell * 4 + 1] = wx * (1.0f - wy);
    wgt[cell * 4 + 2] = (1.0f - wx) * wy;
    wgt[cell * 4 + 3] = wx * wy;
  }
}

__device__ __forceinline__ void load8(const uint2* __restrict__ t,
                                      const int* __restrict__ idx,
                                      uint2* __restrict__ v) {
#pragma unroll
  for (int i = 0; i < 8; ++i) v[i] = t[idx[i]];
}

__device__ __forceinline__ void consume8(const uint2* __restrict__ v,
                                         const float* __restrict__ wgt, float deq,
                                         float* __restrict__ res) {
  float acc[8];
#pragma unroll
  for (int i = 0; i < 8; ++i) acc[i] = 0.0f;
#pragma unroll
  for (int i = 0; i < 8; ++i) {
    float w = wgt[i];
    unsigned lo = v[i].x, hi = v[i].y;
#pragma unroll
    for (int c = 0; c < 4; ++c)
      acc[c] = fmaf((float)(signed char)(lo >> (8 * c)), w, acc[c]);
#pragma unroll
    for (int c = 0; c < 4; ++c)
      acc[4 + c] = fmaf((float)(signed char)(hi >> (8 * c)), w, acc[4 + c]);
  }
#pragma unroll
  for (int i = 0; i < 8; ++i) res[i] = acc[i] * deq;
}

__device__ __forceinline__ void store8nt(float* __restrict__ o, const float* __restrict__ r) {
  f32x4 a = {r[0], r[1], r[2], r[3]};
  f32x4 b = {r[4], r[5], r[6], r[7]};
  __builtin_nontemporal_store(a, (f32x4*)o);
  __builtin_nontemporal_store(b, (f32x4*)(o + 4));
}

__global__ __launch_bounds__(256) void sample_kernel_sorted(
    const f32x4* __restrict__ slots,
    const uint2* __restrict__ t0, const uint2* __restrict__ t1,
    const uint2* __restrict__ t2, const uint2* __restrict__ t3,
    const uint2* __restrict__ t4, const float* __restrict__ deqs,
    float* __restrict__ out, int P) {
  int i0 = blockIdx.x * 512 + (int)threadIdx.x;
  int i1 = i0 + 256;
  bool v0 = i0 < P, v1 = i1 < P;
  f32x4 zero = {0.0f, 0.0f, 0.0f, 0.0f};
  f32x4 s0 = v0 ? __builtin_nontemporal_load(&slots[i0]) : zero;
  f32x4 s1 = v1 ? __builtin_nontemporal_load(&slots[i1]) : zero;
  float xn0 = s0.x, yn0 = s0.y, xn1 = s1.x, yn1 = s1.y;
  int q0 = v0 ? __float_as_int(s0.z) : 0;
  int q1 = v1 ? __float_as_int(s1.z) : 0;
  float d0 = deqs[0], d1 = deqs[1], d2 = deqs[2], d3 = deqs[3], d4 = deqs[4];
  float* o0 = out + (size_t)q0 * 40u;
  float* o1 = out + (size_t)q1 * 40u;

  int ia[8];
  uint2 a0[8], a1[8], b0[8], b1[8];
  float wg[8], res[8];

  level_idx<64>(xn0, yn0, ia);   load8(t0, ia, a0);
  level_idx<64>(xn1, yn1, ia);   load8(t0, ia, a1);
  level_idx<128>(xn0, yn0, ia);  load8(t1, ia, b0);
  level_idx<128>(xn1, yn1, ia);  load8(t1, ia, b1);

  level_weights<64>(xn0, yn0, wg);  consume8(a0, wg, d0, res); if (v0) store8nt(o0 + 0, res);
  level_weights<64>(xn1, yn1, wg);  consume8(a1, wg, d0, res); if (v1) store8nt(o1 + 0, res);
  level_idx<256>(xn0, yn0, ia);  load8(t2, ia, a0);
  level_idx<256>(xn1, yn1, ia);  load8(t2, ia, a1);

  level_weights<128>(xn0, yn0, wg); consume8(b0, wg, d1, res); if (v0) store8nt(o0 + 8, res);
  level_weights<128>(xn1, yn1, wg); consume8(b1, wg, d1, res); if (v1) store8nt(o1 + 8, res);
  level_idx<512>(xn0, yn0, ia);  load8(t3, ia, b0);
  level_idx<512>(xn1, yn1, ia);  load8(t3, ia, b1);

  level_weights<256>(xn0, yn0, wg); consume8(a0, wg, d2, res); if (v0) store8nt(o0 + 16, res);
  level_weights<256>(xn1, yn1, wg); consume8(a1, wg, d2, res); if (v1) store8nt(o1 + 16, res);
  level_idx<1024>(xn0, yn0, ia); load8(t4, ia, a0);
  level_idx<1024>(xn1, yn1, ia); load8(t4, ia, a1);

  level_weights<512>(xn0, yn0, wg);  consume8(b0, wg, d3, res); if (v0) store8nt(o0 + 24, res);
  level_weights<512>(xn1, yn1, wg);  consume8(b1, wg, d3, res); if (v1) store8nt(o1 + 24, res);
  level_weights<1024>(xn0, yn0, wg); consume8(a0, wg, d4, res); if (v0) store8nt(o0 + 32, res);
  level_weights<1024>(xn1, yn1, wg); consume8(a1, wg, d4, res); if (v1) store8nt(o1 + 32, res);
}

// ---- fallback: native layout fp32 direct ----
template <int W>
__device__ __forceinline__ void sample_level_direct(
    const float* __restrict__ t, float xv, float yv, float* __restrict__ o) {
  float acc[8];
#pragma unroll
  for (int i = 0; i < 8; ++i) acc[i] = 0.0f;
  float xn = xv * 2.0f - 1.0f;
  float yn = yv * 2.0f - 1.0f;
#pragma unroll
  for (int cell = 0; cell < 2; ++cell) {
    const float off = 0.5f * (float)cell;
    float ix = (xn + 1.0f) * 0.5f * (float)(W - 1) + off;
    float iy = (yn + 1.0f) * 0.5f * (float)(W - 1) + off;
    float x0f = floorf(ix), y0f = floorf(iy);
    float wx = ix - x0f, wy = iy - y0f;
    int x0 = (int)x0f; x0 = min(max(x0, 0), W - 1);
    int y0 = (int)y0f; y0 = min(max(y0, 0), W - 1);
    int x1 = min(x0 + 1, W - 1);
    int y1 = min(y0 + 1, W - 1);
    float w00 = (1.0f - wx) * (1.0f - wy);
    float w01 = wx * (1.0f - wy);
    float w10 = (1.0f - wx) * wy;
    float w11 = wx * wy;
    const float* b = t + (size_t)cell * 8u * (size_t)W * (size_t)W;
    size_t i00 = (size_t)y0 * W + x0;
    size_t i01 = (size_t)y0 * W + x1;
    size_t i10 = (size_t)y1 * W + x0;
    size_t i11 = (size_t)y1 * W + x1;
#pragma unroll
    for (int c = 0; c < 8; ++c) {
      const float* pc = b + (size_t)c * (size_t)W * (size_t)W;
      acc[c] += pc[i00] * w00 + pc[i01] * w01 + pc[i10] * w10 + pc[i11] * w11;
    }
  }
#pragma unroll
  for (int i = 0; i < 8; ++i) o[i] = acc[i];
}

__global__ __launch_bounds__(256) void sample_kernel_direct(
    const float* __restrict__ x, const float* __restrict__ y,
    const float* __restrict__ t0, const float* __restrict__ t1,
    const float* __restrict__ t2, const float* __restrict__ t3,
    const float* __restrict__ t4, float* __restrict__ out, int P) {
  int p = blockIdx.x * blockDim.x + threadIdx.x;
  if (p >= P) return;
  float xv = x[p];
  float yv = y[p];
  float o[8];
  float* orow = out + (size_t)p * 40u;
  sample_level_direct<64>(t0, xv, yv, o);
#pragma unroll
  for (int i = 0; i < 8; ++i) orow[0 + i] = o[i];
  sample_level_direct<128>(t1, xv, yv, o);
#pragma unroll
  for (int i = 0; i < 8; ++i) orow[8 + i] = o[i];
  sample_level_direct<256>(t2, xv, yv, o);
#pragma unroll
  for (int i = 0; i < 8; ++i) orow[16 + i] = o[i];
  sample_level_direct<512>(t3, xv, yv, o);
#pragma unroll
  for (int i = 0; i < 8; ++i) orow[24 + i] = o[i];
  sample_level_direct<1024>(t4, xv, yv, o);
#pragma unroll
  for (int i = 0; i < 8; ++i) orow[32 + i] = o[i];
}

extern "C" void kernel_launch(void* const* d_in, const int* in_sizes, int n_in,
                              void* d_out, int out_size, void* d_ws, size_t ws_size,
                              hipStream_t stream) {
  const float* x = (const float*)d_in[0];
  const float* y = (const float*)d_in[1];
  const float* tabs[5] = {(const float*)d_in[2], (const float*)d_in[3],
                          (const float*)d_in[4], (const float*)d_in[5],
                          (const float*)d_in[6]};
  float* out = (float*)d_out;
  const int P = in_sizes[0];

  const size_t offs[5] = {0, 8192, 40960, 172032, 696320};
  const size_t total_px = 2793472;
  size_t need = WS_TAB + total_px * sizeof(uint2);

  if (ws_size >= need && P <= 1000448) {
    float* deq = (float*)d_ws;
    float* inv = (float*)((char*)d_ws + 32);
    unsigned* partials = (unsigned*)((char*)d_ws + WS_PART);
    unsigned* hist = (unsigned*)((char*)d_ws + WS_HIST);
    unsigned* starts = (unsigned*)((char*)d_ws + WS_START);
    unsigned* cursor = (unsigned*)((char*)d_ws + WS_CURS);
    f32x4* slots = (f32x4*)((char*)d_ws + WS_SLOT);
    uint2* tb = (uint2*)((char*)d_ws + WS_TAB);

    (void)hipMemsetAsync(hist, 0, NBUCK * sizeof(unsigned), stream);
    absmax_hist_kernel<<<5456 + 2048, 256, 0, stream>>>(
        tabs[0], tabs[1], tabs[2], tabs[3], tabs[4], partials, x, y, P, hist);
    scales_scan_kernel<<<1, 256, 0, stream>>>(partials, deq, inv, hist, starts,
                                              cursor);
    quant_scatter_kernel<<<10912 + 2048, 256, 0, stream>>>(
        tabs[0], tabs[1], tabs[2], tabs[3], tabs[4], tb, inv, x, y, P, cursor,
        slots);
    int blocks = (P + 511) / 512;
    sample_kernel_sorted<<<blocks, 256, 0, stream>>>(
        slots, tb + offs[0], tb + offs[1], tb + offs[2], tb + offs[3],
        tb + offs[4], deq, out, P);
  } else {
    sample_kernel_direct<<<(P + 255) / 256, 256, 0, stream>>>(
        x, y, tabs[0], tabs[1], tabs[2], tabs[3], tabs[4], out, P);
  }
}

// Round 9
// 242.867 us; speedup vs baseline: 2.5353x; 2.5353x over previous
//
#include <hip/hip_runtime.h>

// RES=[64,128,256,512,1024], NF=8, NC=2, P=1e6. out[p*40 + lvl*8 + c], fp32.
//
// Pipeline (fused, deterministic output):
//  memset(hist)
//  K1: absmax partials (blocks [0,5456)) || point histogram (blocks [5456,7504))
//  K2: reduce scales + exclusive scan of 16384 Morton buckets (1 block)
//  K3: int8 quantize (blocks [0,10912)) || sort-scatter (blocks [10912,12960))
//      scatter emits ONE 16B slot {xn, yn, perm, 0} per point
//  K4: sample 2 sorted points/thread, depth-2 level pipeline. Each bilinear
//      row-pair (x0,x0+1) is ONE uint4 gather -> 20 gathers/point (was 40).
//      Border via xL=min(x0,W-2) + branchless select. No NT hints anywhere:
//      L2 write-combining absorbs the scattered 160B output rows (round-8
//      lesson: NT stores broke that, +300% sample time).
//
// d_ws layout (bytes):
//   deq[8] f32        @ 0
//   inv[8] f32        @ 32
//   partials[5456]    @ 64
//   hist[16384]       @ 24576
//   starts[16384]     @ 90112
//   cursor[16384]     @ 155648
//   slots[P] 16B      @ 262144    ({xn,yn,perm,pad})
//   tables (uint2/px) @ 17301504

#define WS_PART 64
#define WS_HIST 24576
#define WS_START 90112
#define WS_CURS 155648
#define WS_SLOT 262144
#define WS_TAB 17301504
#define NBUCK 16384

__device__ __forceinline__ unsigned part1by1(unsigned v) {
  v &= 0x0000FFFFu;
  v = (v | (v << 8)) & 0x00FF00FFu;
  v = (v | (v << 4)) & 0x0F0F0F0Fu;
  v = (v | (v << 2)) & 0x33333333u;
  v = (v | (v << 1)) & 0x55555555u;
  return v;
}

__device__ __forceinline__ int bucket_of(float xv, float yv) {
  int bx = (int)(xv * 128.0f);
  int by = (int)(yv * 128.0f);
  bx = min(max(bx, 0), 127);
  by = min(max(by, 0), 127);
  return (int)(part1by1((unsigned)bx) | (part1by1((unsigned)by) << 1));
}

// ---- K1: absmax partials || histogram ----
__global__ __launch_bounds__(256) void absmax_hist_kernel(
    const float* __restrict__ s0, const float* __restrict__ s1,
    const float* __restrict__ s2, const float* __restrict__ s3,
    const float* __restrict__ s4, unsigned* __restrict__ partials,
    const float* __restrict__ x, const float* __restrict__ y, int P,
    unsigned* __restrict__ hist) {
  int b = blockIdx.x;
  if (b >= 5456) {  // histogram part
    int nb = gridDim.x - 5456;
    int stride = nb * 256;
    for (int p = (b - 5456) * 256 + (int)threadIdx.x; p < P; p += stride)
      atomicAdd(&hist[bucket_of(x[p], y[p])], 1u);
    return;
  }
  __shared__ unsigned red[4];
  const float* src; int n4; int lb; int nb;
  if (b < 16)        { src = s0; n4 = 16384;   lb = 0;    nb = 16; }
  else if (b < 80)   { src = s1; n4 = 65536;   lb = 16;   nb = 64; }
  else if (b < 336)  { src = s2; n4 = 262144;  lb = 80;   nb = 256; }
  else if (b < 1360) { src = s3; n4 = 1048576; lb = 336;  nb = 1024; }
  else               { src = s4; n4 = 4194304; lb = 1360; nb = 4096; }
  int local = b - lb;
  unsigned m = 0;
  for (int k = local * 256 + threadIdx.x; k < n4; k += nb * 256) {
    float4 v = ((const float4*)src)[k];
    unsigned a = __float_as_uint(v.x) & 0x7FFFFFFFu;
    unsigned c = __float_as_uint(v.y) & 0x7FFFFFFFu;
    unsigned d = __float_as_uint(v.z) & 0x7FFFFFFFu;
    unsigned e = __float_as_uint(v.w) & 0x7FFFFFFFu;
    m = max(m, max(max(a, c), max(d, e)));
  }
#pragma unroll
  for (int off = 32; off; off >>= 1)
    m = max(m, (unsigned)__shfl_xor((int)m, off));
  if ((threadIdx.x & 63) == 0) red[threadIdx.x >> 6] = m;
  __syncthreads();
  if (threadIdx.x == 0)
    partials[b] = max(max(red[0], red[1]), max(red[2], red[3]));
}

// ---- K2: reduce scales + scan (one block, 256 threads) ----
__global__ __launch_bounds__(256) void scales_scan_kernel(
    const unsigned* __restrict__ partials, float* __restrict__ deq,
    float* __restrict__ inv, const unsigned* __restrict__ hist,
    unsigned* __restrict__ starts, unsigned* __restrict__ cursor) {
  __shared__ unsigned red[4];
  __shared__ unsigned sums[256];
  int t = (int)threadIdx.x;
  const int lo[5] = {0, 16, 80, 336, 1360};
  const int hi[5] = {16, 80, 336, 1360, 5456};
  for (int l = 0; l < 5; ++l) {
    unsigned m = 0;
    for (int i = lo[l] + t; i < hi[l]; i += 256) m = max(m, partials[i]);
#pragma unroll
    for (int off = 32; off; off >>= 1)
      m = max(m, (unsigned)__shfl_xor((int)m, off));
    if ((t & 63) == 0) red[t >> 6] = m;
    __syncthreads();
    if (t == 0) {
      unsigned r = max(max(red[0], red[1]), max(red[2], red[3]));
      float s = __uint_as_float(r);
      if (!(s > 0.0f)) s = 1e-20f;
      deq[l] = s / 127.0f;
      inv[l] = 127.0f / s;
    }
    __syncthreads();
  }
  unsigned local[64];
  unsigned s = 0;
#pragma unroll
  for (int i = 0; i < 64; ++i) { local[i] = s; s += hist[t * 64 + i]; }
  sums[t] = s;
  __syncthreads();
  for (int off = 1; off < 256; off <<= 1) {
    unsigned v = (t >= off) ? sums[t - off] : 0u;
    __syncthreads();
    sums[t] += v;
    __syncthreads();
  }
  unsigned base = (t == 0) ? 0u : sums[t - 1];
#pragma unroll
  for (int i = 0; i < 64; ++i) {
    unsigned v = base + local[i];
    starts[t * 64 + i] = v;
    cursor[t * 64 + i] = v;
  }
}

// ---- K3: quantize || scatter ----
__global__ __launch_bounds__(256) void quant_scatter_kernel(
    const float* __restrict__ s0, const float* __restrict__ s1,
    const float* __restrict__ s2, const float* __restrict__ s3,
    const float* __restrict__ s4, uint2* __restrict__ tb,
    const float* __restrict__ invp,
    const float* __restrict__ x, const float* __restrict__ y, int P,
    unsigned* __restrict__ cursor, float4* __restrict__ slots) {
  int b = blockIdx.x;
  if (b >= 10912) {  // scatter part
    int nb = gridDim.x - 10912;
    int stride = nb * 256;
    for (int p = (b - 10912) * 256 + (int)threadIdx.x; p < P; p += stride) {
      float xv = x[p], yv = y[p];
      int bk = bucket_of(xv, yv);
      unsigned slot = atomicAdd(&cursor[bk], 1u);
      float4 s;
      s.x = xv * 2.0f - 1.0f;
      s.y = yv * 2.0f - 1.0f;
      s.z = __int_as_float(p);
      s.w = 0.0f;
      slots[slot] = s;
    }
    return;
  }
  const float* src; int HW; int lb; int l; size_t toff;
  if (b < 32)        { src = s0; HW = 4096;    lb = 0;    l = 0; toff = 0; }
  else if (b < 160)  { src = s1; HW = 16384;   lb = 32;   l = 1; toff = 8192; }
  else if (b < 672)  { src = s2; HW = 65536;   lb = 160;  l = 2; toff = 40960; }
  else if (b < 2720) { src = s3; HW = 262144;  lb = 672;  l = 3; toff = 172032; }
  else               { src = s4; HW = 1048576; lb = 2720; l = 4; toff = 696320; }
  int i = (b - lb) * 256 + (int)threadIdx.x;
  float sc = invp[l];
  int cell = i / HW;
  int pix = i - cell * HW;
  const float* s = src + (size_t)cell * 8u * (size_t)HW + (size_t)pix;
  unsigned lov = 0, hiv = 0;
#pragma unroll
  for (int c = 0; c < 4; ++c) {
    int q = (int)rintf(s[(size_t)c * HW] * sc);
    q = min(max(q, -127), 127);
    lov |= ((unsigned)(q & 0xFF)) << (8 * c);
  }
#pragma unroll
  for (int c = 0; c < 4; ++c) {
    int q = (int)rintf(s[(size_t)(c + 4) * HW] * sc);
    q = min(max(q, -127), 127);
    hiv |= ((unsigned)(q & 0xFF)) << (8 * c);
  }
  tb[toff + (size_t)i] = make_uint2(lov, hiv);
}

// ---- sampling ----
// Per level: 4 row-pair addresses (2 cells x 2 rows), 2 edge flags, 8 weights.
template <int W>
__device__ __forceinline__ void level_calc(float xn, float yn,
                                           int* __restrict__ addr,
                                           int& edges,
                                           float* __restrict__ wgt) {
  edges = 0;
#pragma unroll
  for (int cell = 0; cell < 2; ++cell) {
    const float off = 0.5f * (float)cell;
    float ix = (xn + 1.0f) * 0.5f * (float)(W - 1) + off;
    float iy = (yn + 1.0f) * 0.5f * (float)(W - 1) + off;
    float xf = floorf(ix), yf = floorf(iy);
    float wx = ix - xf, wy = iy - yf;
    int x0 = (int)xf; x0 = min(max(x0, 0), W - 1);
    int y0 = (int)yf; y0 = min(max(y0, 0), W - 1);
    int y1 = min(y0 + 1, W - 1);
    int edge = (x0 == W - 1) ? 1 : 0;
    int xL = edge ? (W - 2) : x0;
    edges |= edge << cell;
    int base = cell * W * W;
    addr[cell * 2 + 0] = base + y0 * W + xL;
    addr[cell * 2 + 1] = base + y1 * W + xL;
    wgt[cell * 4 + 0] = (1.0f - wx) * (1.0f - wy);
    wgt[cell * 4 + 1] = wx * (1.0f - wy);
    wgt[cell * 4 + 2] = (1.0f - wx) * wy;
    wgt[cell * 4 + 3] = wx * wy;
  }
}

// 4 uint4 loads: each covers pixels {xL, xL+1} of one row (16B at 8B align).
__device__ __forceinline__ void load4(const uint2* __restrict__ t,
                                      const int* __restrict__ addr,
                                      uint4* __restrict__ v) {
#pragma unroll
  for (int i = 0; i < 4; ++i) v[i] = *(const uint4*)(t + addr[i]);
}

__device__ __forceinline__ void fma_px(unsigned lo, unsigned hi, float w,
                                       float* __restrict__ acc) {
#pragma unroll
  for (int c = 0; c < 4; ++c)
    acc[c] = fmaf((float)(signed char)(lo >> (8 * c)), w, acc[c]);
#pragma unroll
  for (int c = 0; c < 4; ++c)
    acc[4 + c] = fmaf((float)(signed char)(hi >> (8 * c)), w, acc[4 + c]);
}

__device__ __forceinline__ void consume4(const uint4* __restrict__ v, int edges,
                                         const float* __restrict__ wgt, float deq,
                                         float* __restrict__ res) {
  float acc[8];
#pragma unroll
  for (int i = 0; i < 8; ++i) acc[i] = 0.0f;
#pragma unroll
  for (int cell = 0; cell < 2; ++cell) {
    bool e = (edges >> cell) & 1;
    uint4 r0 = v[cell * 2 + 0];
    uint4 r1 = v[cell * 2 + 1];
    unsigned nw_lo = e ? r0.z : r0.x, nw_hi = e ? r0.w : r0.y;
    unsigned sw_lo = e ? r1.z : r1.x, sw_hi = e ? r1.w : r1.y;
    fma_px(nw_lo, nw_hi, wgt[cell * 4 + 0], acc);   // nw
    fma_px(r0.z, r0.w, wgt[cell * 4 + 1], acc);     // ne (always hi pixel)
    fma_px(sw_lo, sw_hi, wgt[cell * 4 + 2], acc);   // sw
    fma_px(r1.z, r1.w, wgt[cell * 4 + 3], acc);     // se
  }
#pragma unroll
  for (int i = 0; i < 8; ++i) res[i] = acc[i] * deq;
}

__device__ __forceinline__ void store8(float* __restrict__ o, const float* __restrict__ r) {
  ((float4*)o)[0] = make_float4(r[0], r[1], r[2], r[3]);
  ((float4*)o)[1] = make_float4(r[4], r[5], r[6], r[7]);
}

__global__ __launch_bounds__(256) void sample_kernel_sorted(
    const float4* __restrict__ slots,
    const uint2* __restrict__ t0, const uint2* __restrict__ t1,
    const uint2* __restrict__ t2, const uint2* __restrict__ t3,
    const uint2* __restrict__ t4, const float* __restrict__ deqs,
    float* __restrict__ out, int P) {
  int i0 = blockIdx.x * 512 + (int)threadIdx.x;
  int i1 = i0 + 256;
  bool v0 = i0 < P, v1 = i1 < P;
  float4 s0 = v0 ? slots[i0] : make_float4(0.f, 0.f, 0.f, 0.f);
  float4 s1 = v1 ? slots[i1] : make_float4(0.f, 0.f, 0.f, 0.f);
  float xn0 = s0.x, yn0 = s0.y, xn1 = s1.x, yn1 = s1.y;
  int q0 = v0 ? __float_as_int(s0.z) : 0;
  int q1 = v1 ? __float_as_int(s1.z) : 0;
  float d0 = deqs[0], d1 = deqs[1], d2 = deqs[2], d3 = deqs[3], d4 = deqs[4];
  float* o0 = out + (size_t)q0 * 40u;
  float* o1 = out + (size_t)q1 * 40u;

  int ia[4];
  uint4 a0[4], a1[4], b0[4], b1[4];
  int ea0, ea1, eb0, eb1, etmp;
  float wg[8], res[8];

  // prologue: L0 + L1 for both points in flight
  level_calc<64>(xn0, yn0, ia, ea0, wg);   load4(t0, ia, a0);
  float wa0[8]; { for (int i = 0; i < 8; ++i) wa0[i] = wg[i]; }
  level_calc<64>(xn1, yn1, ia, ea1, wg);   load4(t0, ia, a1);
  float wa1[8]; { for (int i = 0; i < 8; ++i) wa1[i] = wg[i]; }
  level_calc<128>(xn0, yn0, ia, eb0, wg);  load4(t1, ia, b0);
  float wb0[8]; { for (int i = 0; i < 8; ++i) wb0[i] = wg[i]; }
  level_calc<128>(xn1, yn1, ia, eb1, wg);  load4(t1, ia, b1);
  float wb1[8]; { for (int i = 0; i < 8; ++i) wb1[i] = wg[i]; }

  // consume L0, issue L2
  consume4(a0, ea0, wa0, d0, res); if (v0) store8(o0 + 0, res);
  consume4(a1, ea1, wa1, d0, res); if (v1) store8(o1 + 0, res);
  level_calc<256>(xn0, yn0, ia, etmp, wa0);  load4(t2, ia, a0); ea0 = etmp;
  level_calc<256>(xn1, yn1, ia, etmp, wa1);  load4(t2, ia, a1); ea1 = etmp;

  // consume L1, issue L3
  consume4(b0, eb0, wb0, d1, res); if (v0) store8(o0 + 8, res);
  consume4(b1, eb1, wb1, d1, res); if (v1) store8(o1 + 8, res);
  level_calc<512>(xn0, yn0, ia, etmp, wb0);  load4(t3, ia, b0); eb0 = etmp;
  level_calc<512>(xn1, yn1, ia, etmp, wb1);  load4(t3, ia, b1); eb1 = etmp;

  // consume L2, issue L4
  consume4(a0, ea0, wa0, d2, res); if (v0) store8(o0 + 16, res);
  consume4(a1, ea1, wa1, d2, res); if (v1) store8(o1 + 16, res);
  level_calc<1024>(xn0, yn0, ia, etmp, wa0); load4(t4, ia, a0); ea0 = etmp;
  level_calc<1024>(xn1, yn1, ia, etmp, wa1); load4(t4, ia, a1); ea1 = etmp;

  // consume L3, then L4
  consume4(b0, eb0, wb0, d3, res); if (v0) store8(o0 + 24, res);
  consume4(b1, eb1, wb1, d3, res); if (v1) store8(o1 + 24, res);
  consume4(a0, ea0, wa0, d4, res); if (v0) store8(o0 + 32, res);
  consume4(a1, ea1, wa1, d4, res); if (v1) store8(o1 + 32, res);
}

// ---- fallback: native layout fp32 direct ----
template <int W>
__device__ __forceinline__ void sample_level_direct(
    const float* __restrict__ t, float xv, float yv, float* __restrict__ o) {
  float acc[8];
#pragma unroll
  for (int i = 0; i < 8; ++i) acc[i] = 0.0f;
  float xn = xv * 2.0f - 1.0f;
  float yn = yv * 2.0f - 1.0f;
#pragma unroll
  for (int cell = 0; cell < 2; ++cell) {
    const float off = 0.5f * (float)cell;
    float ix = (xn + 1.0f) * 0.5f * (float)(W - 1) + off;
    float iy = (yn + 1.0f) * 0.5f * (float)(W - 1) + off;
    float x0f = floorf(ix), y0f = floorf(iy);
    float wx = ix - x0f, wy = iy - y0f;
    int x0 = (int)x0f; x0 = min(max(x0, 0), W - 1);
    int y0 = (int)y0f; y0 = min(max(y0, 0), W - 1);
    int x1 = min(x0 + 1, W - 1);
    int y1 = min(y0 + 1, W - 1);
    float w00 = (1.0f - wx) * (1.0f - wy);
    float w01 = wx * (1.0f - wy);
    float w10 = (1.0f - wx) * wy;
    float w11 = wx * wy;
    const float* b = t + (size_t)cell * 8u * (size_t)W * (size_t)W;
    size_t i00 = (size_t)y0 * W + x0;
    size_t i01 = (size_t)y0 * W + x1;
    size_t i10 = (size_t)y1 * W + x0;
    size_t i11 = (size_t)y1 * W + x1;
#pragma unroll
    for (int c = 0; c < 8; ++c) {
      const float* pc = t + (size_t)cell * 8u * (size_t)W * (size_t)W + (size_t)c * (size_t)W * (size_t)W;
      acc[c] += pc[i00] * w00 + pc[i01] * w01 + pc[i10] * w10 + pc[i11] * w11;
    }
    (void)b;
  }
#pragma unroll
  for (int i = 0; i < 8; ++i) o[i] = acc[i];
}

__global__ __launch_bounds__(256) void sample_kernel_direct(
    const float* __restrict__ x, const float* __restrict__ y,
    const float* __restrict__ t0, const float* __restrict__ t1,
    const float* __restrict__ t2, const float* __restrict__ t3,
    const float* __restrict__ t4, float* __restrict__ out, int P) {
  int p = blockIdx.x * blockDim.x + threadIdx.x;
  if (p >= P) return;
  float xv = x[p];
  float yv = y[p];
  float o[8];
  float* orow = out + (size_t)p * 40u;
  sample_level_direct<64>(t0, xv, yv, o);
#pragma unroll
  for (int i = 0; i < 8; ++i) orow[0 + i] = o[i];
  sample_level_direct<128>(t1, xv, yv, o);
#pragma unroll
  for (int i = 0; i < 8; ++i) orow[8 + i] = o[i];
  sample_level_direct<256>(t2, xv, yv, o);
#pragma unroll
  for (int i = 0; i < 8; ++i) orow[16 + i] = o[i];
  sample_level_direct<512>(t3, xv, yv, o);
#pragma unroll
  for (int i = 0; i < 8; ++i) orow[24 + i] = o[i];
  sample_level_direct<1024>(t4, xv, yv, o);
#pragma unroll
  for (int i = 0; i < 8; ++i) orow[32 + i] = o[i];
}

extern "C" void kernel_launch(void* const* d_in, const int* in_sizes, int n_in,
                              void* d_out, int out_size, void* d_ws, size_t ws_size,
                              hipStream_t stream) {
  const float* x = (const float*)d_in[0];
  const float* y = (const float*)d_in[1];
  const float* tabs[5] = {(const float*)d_in[2], (const float*)d_in[3],
                          (const float*)d_in[4], (const float*)d_in[5],
                          (const float*)d_in[6]};
  float* out = (float*)d_out;
  const int P = in_sizes[0];

  const size_t offs[5] = {0, 8192, 40960, 172032, 696320};
  const size_t total_px = 2793472;
  size_t need = WS_TAB + total_px * sizeof(uint2);

  if (ws_size >= need && P <= 1000448) {
    float* deq = (float*)d_ws;
    float* inv = (float*)((char*)d_ws + 32);
    unsigned* partials = (unsigned*)((char*)d_ws + WS_PART);
    unsigned* hist = (unsigned*)((char*)d_ws + WS_HIST);
    unsigned* starts = (unsigned*)((char*)d_ws + WS_START);
    unsigned* cursor = (unsigned*)((char*)d_ws + WS_CURS);
    float4* slots = (float4*)((char*)d_ws + WS_SLOT);
    uint2* tb = (uint2*)((char*)d_ws + WS_TAB);

    (void)hipMemsetAsync(hist, 0, NBUCK * sizeof(unsigned), stream);
    absmax_hist_kernel<<<5456 + 2048, 256, 0, stream>>>(
        tabs[0], tabs[1], tabs[2], tabs[3], tabs[4], partials, x, y, P, hist);
    scales_scan_kernel<<<1, 256, 0, stream>>>(partials, deq, inv, hist, starts,
                                              cursor);
    quant_scatter_kernel<<<10912 + 2048, 256, 0, stream>>>(
        tabs[0], tabs[1], tabs[2], tabs[3], tabs[4], tb, inv, x, y, P, cursor,
        slots);
    int blocks = (P + 511) / 512;
    sample_kernel_sorted<<<blocks, 256, 0, stream>>>(
        slots, tb + offs[0], tb + offs[1], tb + offs[2], tb + offs[3],
        tb + offs[4], deq, out, P);
  } else {
    sample_kernel_direct<<<(P + 255) / 256, 256, 0, stream>>>(
        x, y, tabs[0], tabs[1], tabs[2], tabs[3], tabs[4], out, P);
  }
}

// Round 10
// 239.116 us; speedup vs baseline: 2.5750x; 1.0157x over previous
//
#include <hip/hip_runtime.h>

// RES=[64,128,256,512,1024], NF=8, NC=2, P=1e6. out[p*40 + lvl*8 + c], fp32.
//
// Pipeline (fused, deterministic output):
//  memset(hist)
//  K1: absmax partials || point histogram (16384 Morton buckets, 128x128)
//  K2: reduce scales + exclusive scan (1 block)
//  K3: int8 quantize || sort-scatter (ONE 16B slot {xn,yn,perm,0} per point)
//  K4: TILE kernel: one block per 8-bucket Morton group (4x2 cells). Block
//      stages its 5-level table window (<= ~20KB, proven bound w/ 1px margin)
//      into LDS, then gathers corners via ds_read_b64 (32-bank parallel)
//      instead of L1 divergent loads (~130 cyc/inst, round-9 measurement).
//
// d_ws layout (bytes): deq[8]@0 inv[8]@32 partials@64 hist@24576 starts@90112
//   cursor@155648 slots@262144 tables@17301504

#define WS_PART 64
#define WS_HIST 24576
#define WS_START 90112
#define WS_CURS 155648
#define WS_SLOT 262144
#define WS_TAB 17301504
#define NBUCK 16384
#define LDS_CAP 2944

__device__ __forceinline__ unsigned part1by1(unsigned v) {
  v &= 0x0000FFFFu;
  v = (v | (v << 8)) & 0x00FF00FFu;
  v = (v | (v << 4)) & 0x0F0F0F0Fu;
  v = (v | (v << 2)) & 0x33333333u;
  v = (v | (v << 1)) & 0x55555555u;
  return v;
}

__device__ __forceinline__ unsigned compact1by1(unsigned v) {
  v &= 0x55555555u;
  v = (v | (v >> 1)) & 0x33333333u;
  v = (v | (v >> 2)) & 0x0F0F0F0Fu;
  v = (v | (v >> 4)) & 0x00FF00FFu;
  v = (v | (v >> 8)) & 0x0000FFFFu;
  return v;
}

__device__ __forceinline__ int bucket_of(float xv, float yv) {
  int bx = (int)(xv * 128.0f);
  int by = (int)(yv * 128.0f);
  bx = min(max(bx, 0), 127);
  by = min(max(by, 0), 127);
  return (int)(part1by1((unsigned)bx) | (part1by1((unsigned)by) << 1));
}

// ---- K1: absmax partials || histogram ----
__global__ __launch_bounds__(256) void absmax_hist_kernel(
    const float* __restrict__ s0, const float* __restrict__ s1,
    const float* __restrict__ s2, const float* __restrict__ s3,
    const float* __restrict__ s4, unsigned* __restrict__ partials,
    const float* __restrict__ x, const float* __restrict__ y, int P,
    unsigned* __restrict__ hist) {
  int b = blockIdx.x;
  if (b >= 5456) {
    int nb = gridDim.x - 5456;
    int stride = nb * 256;
    for (int p = (b - 5456) * 256 + (int)threadIdx.x; p < P; p += stride)
      atomicAdd(&hist[bucket_of(x[p], y[p])], 1u);
    return;
  }
  __shared__ unsigned red[4];
  const float* src; int n4; int lb; int nb;
  if (b < 16)        { src = s0; n4 = 16384;   lb = 0;    nb = 16; }
  else if (b < 80)   { src = s1; n4 = 65536;   lb = 16;   nb = 64; }
  else if (b < 336)  { src = s2; n4 = 262144;  lb = 80;   nb = 256; }
  else if (b < 1360) { src = s3; n4 = 1048576; lb = 336;  nb = 1024; }
  else               { src = s4; n4 = 4194304; lb = 1360; nb = 4096; }
  int local = b - lb;
  unsigned m = 0;
  for (int k = local * 256 + threadIdx.x; k < n4; k += nb * 256) {
    float4 v = ((const float4*)src)[k];
    unsigned a = __float_as_uint(v.x) & 0x7FFFFFFFu;
    unsigned c = __float_as_uint(v.y) & 0x7FFFFFFFu;
    unsigned d = __float_as_uint(v.z) & 0x7FFFFFFFu;
    unsigned e = __float_as_uint(v.w) & 0x7FFFFFFFu;
    m = max(m, max(max(a, c), max(d, e)));
  }
#pragma unroll
  for (int off = 32; off; off >>= 1)
    m = max(m, (unsigned)__shfl_xor((int)m, off));
  if ((threadIdx.x & 63) == 0) red[threadIdx.x >> 6] = m;
  __syncthreads();
  if (threadIdx.x == 0)
    partials[b] = max(max(red[0], red[1]), max(red[2], red[3]));
}

// ---- K2: reduce scales + scan ----
__global__ __launch_bounds__(256) void scales_scan_kernel(
    const unsigned* __restrict__ partials, float* __restrict__ deq,
    float* __restrict__ inv, const unsigned* __restrict__ hist,
    unsigned* __restrict__ starts, unsigned* __restrict__ cursor) {
  __shared__ unsigned red[4];
  __shared__ unsigned sums[256];
  int t = (int)threadIdx.x;
  const int lo[5] = {0, 16, 80, 336, 1360};
  const int hi[5] = {16, 80, 336, 1360, 5456};
  for (int l = 0; l < 5; ++l) {
    unsigned m = 0;
    for (int i = lo[l] + t; i < hi[l]; i += 256) m = max(m, partials[i]);
#pragma unroll
    for (int off = 32; off; off >>= 1)
      m = max(m, (unsigned)__shfl_xor((int)m, off));
    if ((t & 63) == 0) red[t >> 6] = m;
    __syncthreads();
    if (t == 0) {
      unsigned r = max(max(red[0], red[1]), max(red[2], red[3]));
      float s = __uint_as_float(r);
      if (!(s > 0.0f)) s = 1e-20f;
      deq[l] = s / 127.0f;
      inv[l] = 127.0f / s;
    }
    __syncthreads();
  }
  unsigned local[64];
  unsigned s = 0;
#pragma unroll
  for (int i = 0; i < 64; ++i) { local[i] = s; s += hist[t * 64 + i]; }
  sums[t] = s;
  __syncthreads();
  for (int off = 1; off < 256; off <<= 1) {
    unsigned v = (t >= off) ? sums[t - off] : 0u;
    __syncthreads();
    sums[t] += v;
    __syncthreads();
  }
  unsigned base = (t == 0) ? 0u : sums[t - 1];
#pragma unroll
  for (int i = 0; i < 64; ++i) {
    unsigned v = base + local[i];
    starts[t * 64 + i] = v;
    cursor[t * 64 + i] = v;
  }
}

// ---- K3: quantize || scatter ----
__global__ __launch_bounds__(256) void quant_scatter_kernel(
    const float* __restrict__ s0, const float* __restrict__ s1,
    const float* __restrict__ s2, const float* __restrict__ s3,
    const float* __restrict__ s4, uint2* __restrict__ tb,
    const float* __restrict__ invp,
    const float* __restrict__ x, const float* __restrict__ y, int P,
    unsigned* __restrict__ cursor, float4* __restrict__ slots) {
  int b = blockIdx.x;
  if (b >= 10912) {
    int nb = gridDim.x - 10912;
    int stride = nb * 256;
    for (int p = (b - 10912) * 256 + (int)threadIdx.x; p < P; p += stride) {
      float xv = x[p], yv = y[p];
      int bk = bucket_of(xv, yv);
      unsigned slot = atomicAdd(&cursor[bk], 1u);
      float4 s;
      s.x = xv * 2.0f - 1.0f;
      s.y = yv * 2.0f - 1.0f;
      s.z = __int_as_float(p);
      s.w = 0.0f;
      slots[slot] = s;
    }
    return;
  }
  const float* src; int HW; int lb; int l; size_t toff;
  if (b < 32)        { src = s0; HW = 4096;    lb = 0;    l = 0; toff = 0; }
  else if (b < 160)  { src = s1; HW = 16384;   lb = 32;   l = 1; toff = 8192; }
  else if (b < 672)  { src = s2; HW = 65536;   lb = 160;  l = 2; toff = 40960; }
  else if (b < 2720) { src = s3; HW = 262144;  lb = 672;  l = 3; toff = 172032; }
  else               { src = s4; HW = 1048576; lb = 2720; l = 4; toff = 696320; }
  int i = (b - lb) * 256 + (int)threadIdx.x;
  float sc = invp[l];
  int cell = i / HW;
  int pix = i - cell * HW;
  const float* s = src + (size_t)cell * 8u * (size_t)HW + (size_t)pix;
  unsigned lov = 0, hiv = 0;
#pragma unroll
  for (int c = 0; c < 4; ++c) {
    int q = (int)rintf(s[(size_t)c * HW] * sc);
    q = min(max(q, -127), 127);
    lov |= ((unsigned)(q & 0xFF)) << (8 * c);
  }
#pragma unroll
  for (int c = 0; c < 4; ++c) {
    int q = (int)rintf(s[(size_t)(c + 4) * HW] * sc);
    q = min(max(q, -127), 127);
    hiv |= ((unsigned)(q & 0xFF)) << (8 * c);
  }
  tb[toff + (size_t)i] = make_uint2(lov, hiv);
}

// ---- K4: tile sample ----
struct Win { int ixmin, iymin, ww, wh, base; };

template <int W>
__device__ __forceinline__ Win mkwin(float xlo, float xhi, float ylo, float yhi,
                                     int base) {
  const float s = (float)(W - 1);
  Win w;
  w.ixmin = max(0, (int)floorf(xlo * s) - 1);
  int ixmax = min(W - 1, (int)floorf(xhi * s + 0.5f) + 2);
  w.iymin = max(0, (int)floorf(ylo * s) - 1);
  int iymax = min(W - 1, (int)floorf(yhi * s + 0.5f) + 2);
  w.ww = ixmax - w.ixmin + 1;
  w.wh = iymax - w.iymin + 1;
  w.base = base;
  return w;
}

template <int W>
__device__ __forceinline__ void stage(uint2* __restrict__ lds, const Win& w,
                                      const uint2* __restrict__ t) {
  int n = w.ww * w.wh;
  for (int i = (int)threadIdx.x; i < 2 * n; i += 256) {
    int cell = i >= n;
    int j = cell ? i - n : i;
    int r = j / w.ww;
    int c = j - r * w.ww;
    lds[w.base + i] = t[cell * W * W + (w.iymin + r) * W + (w.ixmin + c)];
  }
}

__device__ __forceinline__ void fma_px(unsigned lo, unsigned hi, float w,
                                       float* __restrict__ acc) {
#pragma unroll
  for (int c = 0; c < 4; ++c)
    acc[c] = fmaf((float)(signed char)(lo >> (8 * c)), w, acc[c]);
#pragma unroll
  for (int c = 0; c < 4; ++c)
    acc[4 + c] = fmaf((float)(signed char)(hi >> (8 * c)), w, acc[4 + c]);
}

template <int W>
__device__ __forceinline__ void sample_lvl(const uint2* __restrict__ lds,
                                           const Win& w, bool use_lds,
                                           const uint2* __restrict__ t,
                                           float xn, float yn, float deq,
                                           float* __restrict__ res) {
  const float s = (float)(W - 1);
  float acc[8];
#pragma unroll
  for (int i = 0; i < 8; ++i) acc[i] = 0.0f;
#pragma unroll
  for (int cell = 0; cell < 2; ++cell) {
    const float off = 0.5f * (float)cell;
    float ix = (xn + 1.0f) * 0.5f * s + off;
    float iy = (yn + 1.0f) * 0.5f * s + off;
    float xf = floorf(ix), yf = floorf(iy);
    float wx = ix - xf, wy = iy - yf;
    int x0 = min(max((int)xf, 0), W - 1);
    int y0 = min(max((int)yf, 0), W - 1);
    int x1 = min(x0 + 1, W - 1);
    int y1 = min(y0 + 1, W - 1);
    uint2 c00, c01, c10, c11;
    if (use_lds) {
      int cb = w.base + cell * (w.ww * w.wh) - w.ixmin;
      int r0 = cb + (y0 - w.iymin) * w.ww;
      int r1 = cb + (y1 - w.iymin) * w.ww;
      c00 = lds[r0 + x0]; c01 = lds[r0 + x1];
      c10 = lds[r1 + x0]; c11 = lds[r1 + x1];
    } else {
      const uint2* b = t + cell * W * W;
      c00 = b[y0 * W + x0]; c01 = b[y0 * W + x1];
      c10 = b[y1 * W + x0]; c11 = b[y1 * W + x1];
    }
    float w00 = (1.0f - wx) * (1.0f - wy);
    float w01 = wx * (1.0f - wy);
    float w10 = (1.0f - wx) * wy;
    float w11 = wx * wy;
    fma_px(c00.x, c00.y, w00, acc);
    fma_px(c01.x, c01.y, w01, acc);
    fma_px(c10.x, c10.y, w10, acc);
    fma_px(c11.x, c11.y, w11, acc);
  }
#pragma unroll
  for (int i = 0; i < 8; ++i) res[i] = acc[i] * deq;
}

__device__ __forceinline__ void store8(float* __restrict__ o,
                                       const float* __restrict__ r) {
  ((float4*)o)[0] = make_float4(r[0], r[1], r[2], r[3]);
  ((float4*)o)[1] = make_float4(r[4], r[5], r[6], r[7]);
}

__global__ __launch_bounds__(256) void sample_tile_kernel(
    const float4* __restrict__ slots, const unsigned* __restrict__ starts,
    const uint2* __restrict__ t0, const uint2* __restrict__ t1,
    const uint2* __restrict__ t2, const uint2* __restrict__ t3,
    const uint2* __restrict__ t4, const float* __restrict__ deqs,
    float* __restrict__ out, int P) {
  __shared__ uint2 lds[LDS_CAP];
  int g = blockIdx.x;  // 0..2047, 8-bucket Morton group
  int s_lo = (int)starts[g << 3];
  int s_hi = (g == 2047) ? P : (int)starts[(g << 3) + 8];
  if (s_lo >= s_hi) return;

  unsigned code = (unsigned)g << 3;
  int bx = (int)compact1by1(code);        // multiple of 4
  int by = (int)compact1by1(code >> 1);   // multiple of 2
  float xlo = (float)bx * (1.0f / 128.0f);
  float xhi = (float)(bx + 4) * (1.0f / 128.0f);
  float ylo = (float)by * (1.0f / 128.0f);
  float yhi = (float)(by + 2) * (1.0f / 128.0f);

  Win w0 = mkwin<64>(xlo, xhi, ylo, yhi, 0);
  Win w1 = mkwin<128>(xlo, xhi, ylo, yhi, w0.base + 2 * w0.ww * w0.wh);
  Win w2 = mkwin<256>(xlo, xhi, ylo, yhi, w1.base + 2 * w1.ww * w1.wh);
  Win w3 = mkwin<512>(xlo, xhi, ylo, yhi, w2.base + 2 * w2.ww * w2.wh);
  Win w4 = mkwin<1024>(xlo, xhi, ylo, yhi, w3.base + 2 * w3.ww * w3.wh);
  int total = w4.base + 2 * w4.ww * w4.wh;
  bool use_lds = (total <= LDS_CAP);

  if (use_lds) {
    stage<64>(lds, w0, t0);
    stage<128>(lds, w1, t1);
    stage<256>(lds, w2, t2);
    stage<512>(lds, w3, t3);
    stage<1024>(lds, w4, t4);
    __syncthreads();
  }

  float d0 = deqs[0], d1 = deqs[1], d2 = deqs[2], d3 = deqs[3], d4 = deqs[4];
  for (int i = s_lo + (int)threadIdx.x; i < s_hi; i += 256) {
    float4 sl = slots[i];
    float xn = sl.x, yn = sl.y;
    int q = __float_as_int(sl.z);
    float* orow = out + (size_t)q * 40u;
    float res[8];
    sample_lvl<64>(lds, w0, use_lds, t0, xn, yn, d0, res);  store8(orow + 0, res);
    sample_lvl<128>(lds, w1, use_lds, t1, xn, yn, d1, res); store8(orow + 8, res);
    sample_lvl<256>(lds, w2, use_lds, t2, xn, yn, d2, res); store8(orow + 16, res);
    sample_lvl<512>(lds, w3, use_lds, t3, xn, yn, d3, res); store8(orow + 24, res);
    sample_lvl<1024>(lds, w4, use_lds, t4, xn, yn, d4, res); store8(orow + 32, res);
  }
}

// ---- fallback: native layout fp32 direct ----
template <int W>
__device__ __forceinline__ void sample_level_direct(
    const float* __restrict__ t, float xv, float yv, float* __restrict__ o) {
  float acc[8];
#pragma unroll
  for (int i = 0; i < 8; ++i) acc[i] = 0.0f;
  float xn = xv * 2.0f - 1.0f;
  float yn = yv * 2.0f - 1.0f;
#pragma unroll
  for (int cell = 0; cell < 2; ++cell) {
    const float off = 0.5f * (float)cell;
    float ix = (xn + 1.0f) * 0.5f * (float)(W - 1) + off;
    float iy = (yn + 1.0f) * 0.5f * (float)(W - 1) + off;
    float x0f = floorf(ix), y0f = floorf(iy);
    float wx = ix - x0f, wy = iy - y0f;
    int x0 = (int)x0f; x0 = min(max(x0, 0), W - 1);
    int y0 = (int)y0f; y0 = min(max(y0, 0), W - 1);
    int x1 = min(x0 + 1, W - 1);
    int y1 = min(y0 + 1, W - 1);
    float w00 = (1.0f - wx) * (1.0f - wy);
    float w01 = wx * (1.0f - wy);
    float w10 = (1.0f - wx) * wy;
    float w11 = wx * wy;
    size_t i00 = (size_t)y0 * W + x0;
    size_t i01 = (size_t)y0 * W + x1;
    size_t i10 = (size_t)y1 * W + x0;
    size_t i11 = (size_t)y1 * W + x1;
#pragma unroll
    for (int c = 0; c < 8; ++c) {
      const float* pc = t + (size_t)cell * 8u * (size_t)W * (size_t)W +
                        (size_t)c * (size_t)W * (size_t)W;
      acc[c] += pc[i00] * w00 + pc[i01] * w01 + pc[i10] * w10 + pc[i11] * w11;
    }
  }
#pragma unroll
  for (int i = 0; i < 8; ++i) o[i] = acc[i];
}

__global__ __launch_bounds__(256) void sample_kernel_direct(
    const float* __restrict__ x, const float* __restrict__ y,
    const float* __restrict__ t0, const float* __restrict__ t1,
    const float* __restrict__ t2, const float* __restrict__ t3,
    const float* __restrict__ t4, float* __restrict__ out, int P) {
  int p = blockIdx.x * blockDim.x + threadIdx.x;
  if (p >= P) return;
  float xv = x[p];
  float yv = y[p];
  float o[8];
  float* orow = out + (size_t)p * 40u;
  sample_level_direct<64>(t0, xv, yv, o);
#pragma unroll
  for (int i = 0; i < 8; ++i) orow[0 + i] = o[i];
  sample_level_direct<128>(t1, xv, yv, o);
#pragma unroll
  for (int i = 0; i < 8; ++i) orow[8 + i] = o[i];
  sample_level_direct<256>(t2, xv, yv, o);
#pragma unroll
  for (int i = 0; i < 8; ++i) orow[16 + i] = o[i];
  sample_level_direct<512>(t3, xv, yv, o);
#pragma unroll
  for (int i = 0; i < 8; ++i) orow[24 + i] = o[i];
  sample_level_direct<1024>(t4, xv, yv, o);
#pragma unroll
  for (int i = 0; i < 8; ++i) orow[32 + i] = o[i];
}

extern "C" void kernel_launch(void* const* d_in, const int* in_sizes, int n_in,
                              void* d_out, int out_size, void* d_ws, size_t ws_size,
                              hipStream_t stream) {
  const float* x = (const float*)d_in[0];
  const float* y = (const float*)d_in[1];
  const float* tabs[5] = {(const float*)d_in[2], (const float*)d_in[3],
                          (const float*)d_in[4], (const float*)d_in[5],
                          (const float*)d_in[6]};
  float* out = (float*)d_out;
  const int P = in_sizes[0];

  const size_t offs[5] = {0, 8192, 40960, 172032, 696320};
  const size_t total_px = 2793472;
  size_t need = WS_TAB + total_px * sizeof(uint2);

  if (ws_size >= need && P <= 1000448) {
    float* deq = (float*)d_ws;
    float* inv = (float*)((char*)d_ws + 32);
    unsigned* partials = (unsigned*)((char*)d_ws + WS_PART);
    unsigned* hist = (unsigned*)((char*)d_ws + WS_HIST);
    unsigned* starts = (unsigned*)((char*)d_ws + WS_START);
    unsigned* cursor = (unsigned*)((char*)d_ws + WS_CURS);
    float4* slots = (float4*)((char*)d_ws + WS_SLOT);
    uint2* tb = (uint2*)((char*)d_ws + WS_TAB);

    (void)hipMemsetAsync(hist, 0, NBUCK * sizeof(unsigned), stream);
    absmax_hist_kernel<<<5456 + 2048, 256, 0, stream>>>(
        tabs[0], tabs[1], tabs[2], tabs[3], tabs[4], partials, x, y, P, hist);
    scales_scan_kernel<<<1, 256, 0, stream>>>(partials, deq, inv, hist, starts,
                                              cursor);
    quant_scatter_kernel<<<10912 + 2048, 256, 0, stream>>>(
        tabs[0], tabs[1], tabs[2], tabs[3], tabs[4], tb, inv, x, y, P, cursor,
        slots);
    sample_tile_kernel<<<2048, 256, 0, stream>>>(
        slots, starts, tb + offs[0], tb + offs[1], tb + offs[2], tb + offs[3],
        tb + offs[4], deq, out, P);
  } else {
    sample_kernel_direct<<<(P + 255) / 256, 256, 0, stream>>>(
        x, y, tabs[0], tabs[1], tabs[2], tabs[3], tabs[4], out, P);
  }
}

// Round 11
// 208.471 us; speedup vs baseline: 2.9536x; 1.1470x over previous
//
#include <hip/hip_runtime.h>

// RES=[64,128,256,512,1024], NF=8, NC=2, P=1e6. out[p*40 + lvl*8 + c], fp32.
//
// Pipeline (fixed-capacity binning — no histogram, no scan):
//  memset(cursor+ovf_cnt)
//  K1: absmax partials (blocks [0,5456)) || direct scatter (blocks [5456,7504)):
//      g = 2x2-cell group of 128-grid (4096 groups, row-major);
//      slot = atomicAdd(cursor[g]); slot<CAP -> perm/sxy at g*CAP+slot,
//      else overflow list (expected ~0 for uniform points; both paths compute
//      bit-identical results -> deterministic output).
//  K2: finalize scales (1 tiny block)
//  K3: quantize tables to int8 channel-last (uint2/pixel)
//  K4: tile sample: block g stages its 5-level window (<=1552 uint2 = 12.8KB
//      proven bound) into LDS; gathers via ds_read; blocks [4096,4128) handle
//      overflow via global path.
//
// d_ws layout (bytes):
//   deq[8]@0  inv[8]@32  partials[5456]@64
//   cursor[4096]@24576  ovf_cnt@40960
//   ovf[524288]@65536  perm[4096*304]@2162688  sxy[4096*304]f2@7143424
//   tables@17301504

#define WS_PART 64
#define WS_CURS 24576
#define WS_OVFC 40960
#define WS_OVF 65536
#define WS_PERM 2162688
#define WS_SXY 7143424
#define WS_TAB 17301504
#define NGRP 4096
#define CAP 304
#define OVF_CAP 524288
#define LDS_CAP 1600

// ---- K1: absmax partials || direct scatter ----
__global__ __launch_bounds__(256) void absmax_scatter_kernel(
    const float* __restrict__ s0, const float* __restrict__ s1,
    const float* __restrict__ s2, const float* __restrict__ s3,
    const float* __restrict__ s4, unsigned* __restrict__ partials,
    const float* __restrict__ x, const float* __restrict__ y, int P,
    unsigned* __restrict__ cursor, unsigned* __restrict__ ovf_cnt,
    int* __restrict__ ovf, int* __restrict__ perm, float2* __restrict__ sxy) {
  int b = blockIdx.x;
  if (b >= 5456) {  // scatter part
    int stride = (gridDim.x - 5456) * 256;
    for (int p = (b - 5456) * 256 + (int)threadIdx.x; p < P; p += stride) {
      float xv = x[p], yv = y[p];
      int bx = min(max((int)(xv * 128.0f), 0), 127);
      int by = min(max((int)(yv * 128.0f), 0), 127);
      int g = (by >> 1) * 64 + (bx >> 1);
      unsigned s = atomicAdd(&cursor[g], 1u);
      if (s < CAP) {
        int slot = g * CAP + (int)s;
        perm[slot] = p;
        sxy[slot] = make_float2(xv * 2.0f - 1.0f, yv * 2.0f - 1.0f);
      } else {
        unsigned o = atomicAdd(ovf_cnt, 1u);
        if (o < OVF_CAP) ovf[o] = p;
      }
    }
    return;
  }
  __shared__ unsigned red[4];
  const float* src; int n4; int lb; int nb;
  if (b < 16)        { src = s0; n4 = 16384;   lb = 0;    nb = 16; }
  else if (b < 80)   { src = s1; n4 = 65536;   lb = 16;   nb = 64; }
  else if (b < 336)  { src = s2; n4 = 262144;  lb = 80;   nb = 256; }
  else if (b < 1360) { src = s3; n4 = 1048576; lb = 336;  nb = 1024; }
  else               { src = s4; n4 = 4194304; lb = 1360; nb = 4096; }
  int local = b - lb;
  unsigned m = 0;
  for (int k = local * 256 + threadIdx.x; k < n4; k += nb * 256) {
    float4 v = ((const float4*)src)[k];
    unsigned a = __float_as_uint(v.x) & 0x7FFFFFFFu;
    unsigned c = __float_as_uint(v.y) & 0x7FFFFFFFu;
    unsigned d = __float_as_uint(v.z) & 0x7FFFFFFFu;
    unsigned e = __float_as_uint(v.w) & 0x7FFFFFFFu;
    m = max(m, max(max(a, c), max(d, e)));
  }
#pragma unroll
  for (int off = 32; off; off >>= 1)
    m = max(m, (unsigned)__shfl_xor((int)m, off));
  if ((threadIdx.x & 63) == 0) red[threadIdx.x >> 6] = m;
  __syncthreads();
  if (threadIdx.x == 0)
    partials[b] = max(max(red[0], red[1]), max(red[2], red[3]));
}

// ---- K2: finalize scales ----
__global__ __launch_bounds__(256) void finalize_scales_kernel(
    const unsigned* __restrict__ partials, float* __restrict__ deq,
    float* __restrict__ inv) {
  __shared__ unsigned red[4];
  int t = (int)threadIdx.x;
  const int lo[5] = {0, 16, 80, 336, 1360};
  const int hi[5] = {16, 80, 336, 1360, 5456};
  for (int l = 0; l < 5; ++l) {
    unsigned m = 0;
    for (int i = lo[l] + t; i < hi[l]; i += 256) m = max(m, partials[i]);
#pragma unroll
    for (int off = 32; off; off >>= 1)
      m = max(m, (unsigned)__shfl_xor((int)m, off));
    if ((t & 63) == 0) red[t >> 6] = m;
    __syncthreads();
    if (t == 0) {
      unsigned r = max(max(red[0], red[1]), max(red[2], red[3]));
      float s = __uint_as_float(r);
      if (!(s > 0.0f)) s = 1e-20f;
      deq[l] = s / 127.0f;
      inv[l] = 127.0f / s;
    }
    __syncthreads();
  }
}

// ---- K3: quantize ----
__global__ __launch_bounds__(256) void quant_kernel(
    const float* __restrict__ s0, const float* __restrict__ s1,
    const float* __restrict__ s2, const float* __restrict__ s3,
    const float* __restrict__ s4, uint2* __restrict__ tb,
    const float* __restrict__ invp) {
  int b = blockIdx.x;
  const float* src; int HW; int lb; int l; size_t toff;
  if (b < 32)        { src = s0; HW = 4096;    lb = 0;    l = 0; toff = 0; }
  else if (b < 160)  { src = s1; HW = 16384;   lb = 32;   l = 1; toff = 8192; }
  else if (b < 672)  { src = s2; HW = 65536;   lb = 160;  l = 2; toff = 40960; }
  else if (b < 2720) { src = s3; HW = 262144;  lb = 672;  l = 3; toff = 172032; }
  else               { src = s4; HW = 1048576; lb = 2720; l = 4; toff = 696320; }
  int i = (b - lb) * 256 + (int)threadIdx.x;
  float sc = invp[l];
  int cell = i / HW;
  int pix = i - cell * HW;
  const float* s = src + (size_t)cell * 8u * (size_t)HW + (size_t)pix;
  unsigned lov = 0, hiv = 0;
#pragma unroll
  for (int c = 0; c < 4; ++c) {
    int q = (int)rintf(s[(size_t)c * HW] * sc);
    q = min(max(q, -127), 127);
    lov |= ((unsigned)(q & 0xFF)) << (8 * c);
  }
#pragma unroll
  for (int c = 0; c < 4; ++c) {
    int q = (int)rintf(s[(size_t)(c + 4) * HW] * sc);
    q = min(max(q, -127), 127);
    hiv |= ((unsigned)(q & 0xFF)) << (8 * c);
  }
  tb[toff + (size_t)i] = make_uint2(lov, hiv);
}

// ---- K4: tile sample ----
struct Win { int ixmin, iymin, ww, wh, base; };

template <int W>
__device__ __forceinline__ Win mkwin(float xlo, float xhi, float ylo, float yhi,
                                     int base) {
  const float s = (float)(W - 1);
  Win w;
  w.ixmin = max(0, (int)floorf(xlo * s) - 1);
  int ixmax = min(W - 1, (int)floorf(xhi * s + 0.5f) + 2);
  w.iymin = max(0, (int)floorf(ylo * s) - 1);
  int iymax = min(W - 1, (int)floorf(yhi * s + 0.5f) + 2);
  w.ww = ixmax - w.ixmin + 1;
  w.wh = iymax - w.iymin + 1;
  w.base = base;
  return w;
}

template <int W>
__device__ __forceinline__ void stage(uint2* __restrict__ lds, const Win& w,
                                      const uint2* __restrict__ t) {
  int n = w.ww * w.wh;
  for (int i = (int)threadIdx.x; i < 2 * n; i += 256) {
    int cell = i >= n;
    int j = cell ? i - n : i;
    int r = j / w.ww;
    int c = j - r * w.ww;
    lds[w.base + i] = t[cell * W * W + (w.iymin + r) * W + (w.ixmin + c)];
  }
}

__device__ __forceinline__ void fma_px(unsigned lo, unsigned hi, float w,
                                       float* __restrict__ acc) {
#pragma unroll
  for (int c = 0; c < 4; ++c)
    acc[c] = fmaf((float)(signed char)(lo >> (8 * c)), w, acc[c]);
#pragma unroll
  for (int c = 0; c < 4; ++c)
    acc[4 + c] = fmaf((float)(signed char)(hi >> (8 * c)), w, acc[4 + c]);
}

template <int W>
__device__ __forceinline__ void sample_lvl(const uint2* __restrict__ lds,
                                           const Win& w, bool use_lds,
                                           const uint2* __restrict__ t,
                                           float xn, float yn, float deq,
                                           float* __restrict__ res) {
  const float s = (float)(W - 1);
  float acc[8];
#pragma unroll
  for (int i = 0; i < 8; ++i) acc[i] = 0.0f;
#pragma unroll
  for (int cell = 0; cell < 2; ++cell) {
    const float off = 0.5f * (float)cell;
    float ix = (xn + 1.0f) * 0.5f * s + off;
    float iy = (yn + 1.0f) * 0.5f * s + off;
    float xf = floorf(ix), yf = floorf(iy);
    float wx = ix - xf, wy = iy - yf;
    int x0 = min(max((int)xf, 0), W - 1);
    int y0 = min(max((int)yf, 0), W - 1);
    int x1 = min(x0 + 1, W - 1);
    int y1 = min(y0 + 1, W - 1);
    uint2 c00, c01, c10, c11;
    if (use_lds) {
      int cb = w.base + cell * (w.ww * w.wh) - w.ixmin;
      int r0 = cb + (y0 - w.iymin) * w.ww;
      int r1 = cb + (y1 - w.iymin) * w.ww;
      c00 = lds[r0 + x0]; c01 = lds[r0 + x1];
      c10 = lds[r1 + x0]; c11 = lds[r1 + x1];
    } else {
      const uint2* b = t + cell * W * W;
      c00 = b[y0 * W + x0]; c01 = b[y0 * W + x1];
      c10 = b[y1 * W + x0]; c11 = b[y1 * W + x1];
    }
    float w00 = (1.0f - wx) * (1.0f - wy);
    float w01 = wx * (1.0f - wy);
    float w10 = (1.0f - wx) * wy;
    float w11 = wx * wy;
    fma_px(c00.x, c00.y, w00, acc);
    fma_px(c01.x, c01.y, w01, acc);
    fma_px(c10.x, c10.y, w10, acc);
    fma_px(c11.x, c11.y, w11, acc);
  }
#pragma unroll
  for (int i = 0; i < 8; ++i) res[i] = acc[i] * deq;
}

__device__ __forceinline__ void store8(float* __restrict__ o,
                                       const float* __restrict__ r) {
  ((float4*)o)[0] = make_float4(r[0], r[1], r[2], r[3]);
  ((float4*)o)[1] = make_float4(r[4], r[5], r[6], r[7]);
}

__global__ __launch_bounds__(256) void sample_tile_kernel(
    const float2* __restrict__ sxy, const int* __restrict__ perm,
    const unsigned* __restrict__ cursor, const unsigned* __restrict__ ovf_cnt,
    const int* __restrict__ ovf,
    const float* __restrict__ x, const float* __restrict__ y,
    const uint2* __restrict__ t0, const uint2* __restrict__ t1,
    const uint2* __restrict__ t2, const uint2* __restrict__ t3,
    const uint2* __restrict__ t4, const float* __restrict__ deqs,
    float* __restrict__ out, int P) {
  __shared__ uint2 lds[LDS_CAP];
  int g = blockIdx.x;
  float d0 = deqs[0], d1 = deqs[1], d2 = deqs[2], d3 = deqs[3], d4 = deqs[4];
  Win wdum = {0, 0, 1, 1, 0};

  if (g >= NGRP) {  // overflow path (expected empty)
    int n = min((int)*ovf_cnt, OVF_CAP);
    int stride = (gridDim.x - NGRP) * 256;
    for (int i = (g - NGRP) * 256 + (int)threadIdx.x; i < n; i += stride) {
      int p = ovf[i];
      float xn = x[p] * 2.0f - 1.0f;
      float yn = y[p] * 2.0f - 1.0f;
      float* orow = out + (size_t)p * 40u;
      float res[8];
      sample_lvl<64>(lds, wdum, false, t0, xn, yn, d0, res);   store8(orow + 0, res);
      sample_lvl<128>(lds, wdum, false, t1, xn, yn, d1, res);  store8(orow + 8, res);
      sample_lvl<256>(lds, wdum, false, t2, xn, yn, d2, res);  store8(orow + 16, res);
      sample_lvl<512>(lds, wdum, false, t3, xn, yn, d3, res);  store8(orow + 24, res);
      sample_lvl<1024>(lds, wdum, false, t4, xn, yn, d4, res); store8(orow + 32, res);
    }
    return;
  }

  int cnt = min((int)cursor[g], CAP);
  if (cnt == 0) return;

  int gx = g & 63, gy = g >> 6;
  float xlo = (float)gx * (1.0f / 64.0f);
  float xhi = (float)(gx + 1) * (1.0f / 64.0f);
  float ylo = (float)gy * (1.0f / 64.0f);
  float yhi = (float)(gy + 1) * (1.0f / 64.0f);

  Win w0 = mkwin<64>(xlo, xhi, ylo, yhi, 0);
  Win w1 = mkwin<128>(xlo, xhi, ylo, yhi, w0.base + 2 * w0.ww * w0.wh);
  Win w2 = mkwin<256>(xlo, xhi, ylo, yhi, w1.base + 2 * w1.ww * w1.wh);
  Win w3 = mkwin<512>(xlo, xhi, ylo, yhi, w2.base + 2 * w2.ww * w2.wh);
  Win w4 = mkwin<1024>(xlo, xhi, ylo, yhi, w3.base + 2 * w3.ww * w3.wh);
  int total = w4.base + 2 * w4.ww * w4.wh;
  bool use_lds = (total <= LDS_CAP);

  if (use_lds) {
    stage<64>(lds, w0, t0);
    stage<128>(lds, w1, t1);
    stage<256>(lds, w2, t2);
    stage<512>(lds, w3, t3);
    stage<1024>(lds, w4, t4);
    __syncthreads();
  }

  const float2* gsxy = sxy + g * CAP;
  const int* gperm = perm + g * CAP;
  for (int i = (int)threadIdx.x; i < cnt; i += 256) {
    float2 c = gsxy[i];
    int q = gperm[i];
    float xn = c.x, yn = c.y;
    float* orow = out + (size_t)q * 40u;
    float res[8];
    sample_lvl<64>(lds, w0, use_lds, t0, xn, yn, d0, res);   store8(orow + 0, res);
    sample_lvl<128>(lds, w1, use_lds, t1, xn, yn, d1, res);  store8(orow + 8, res);
    sample_lvl<256>(lds, w2, use_lds, t2, xn, yn, d2, res);  store8(orow + 16, res);
    sample_lvl<512>(lds, w3, use_lds, t3, xn, yn, d3, res);  store8(orow + 24, res);
    sample_lvl<1024>(lds, w4, use_lds, t4, xn, yn, d4, res); store8(orow + 32, res);
  }
}

// ---- fallback: native layout fp32 direct ----
template <int W>
__device__ __forceinline__ void sample_level_direct(
    const float* __restrict__ t, float xv, float yv, float* __restrict__ o) {
  float acc[8];
#pragma unroll
  for (int i = 0; i < 8; ++i) acc[i] = 0.0f;
  float xn = xv * 2.0f - 1.0f;
  float yn = yv * 2.0f - 1.0f;
#pragma unroll
  for (int cell = 0; cell < 2; ++cell) {
    const float off = 0.5f * (float)cell;
    float ix = (xn + 1.0f) * 0.5f * (float)(W - 1) + off;
    float iy = (yn + 1.0f) * 0.5f * (float)(W - 1) + off;
    float x0f = floorf(ix), y0f = floorf(iy);
    float wx = ix - x0f, wy = iy - y0f;
    int x0 = (int)x0f; x0 = min(max(x0, 0), W - 1);
    int y0 = (int)y0f; y0 = min(max(y0, 0), W - 1);
    int x1 = min(x0 + 1, W - 1);
    int y1 = min(y0 + 1, W - 1);
    float w00 = (1.0f - wx) * (1.0f - wy);
    float w01 = wx * (1.0f - wy);
    float w10 = (1.0f - wx) * wy;
    float w11 = wx * wy;
    size_t i00 = (size_t)y0 * W + x0;
    size_t i01 = (size_t)y0 * W + x1;
    size_t i10 = (size_t)y1 * W + x0;
    size_t i11 = (size_t)y1 * W + x1;
#pragma unroll
    for (int c = 0; c < 8; ++c) {
      const float* pc = t + (size_t)cell * 8u * (size_t)W * (size_t)W +
                        (size_t)c * (size_t)W * (size_t)W;
      acc[c] += pc[i00] * w00 + pc[i01] * w01 + pc[i10] * w10 + pc[i11] * w11;
    }
  }
#pragma unroll
  for (int i = 0; i < 8; ++i) o[i] = acc[i];
}

__global__ __launch_bounds__(256) void sample_kernel_direct(
    const float* __restrict__ x, const float* __restrict__ y,
    const float* __restrict__ t0, const float* __restrict__ t1,
    const float* __restrict__ t2, const float* __restrict__ t3,
    const float* __restrict__ t4, float* __restrict__ out, int P) {
  int p = blockIdx.x * blockDim.x + threadIdx.x;
  if (p >= P) return;
  float xv = x[p];
  float yv = y[p];
  float o[8];
  float* orow = out + (size_t)p * 40u;
  sample_level_direct<64>(t0, xv, yv, o);
#pragma unroll
  for (int i = 0; i < 8; ++i) orow[0 + i] = o[i];
  sample_level_direct<128>(t1, xv, yv, o);
#pragma unroll
  for (int i = 0; i < 8; ++i) orow[8 + i] = o[i];
  sample_level_direct<256>(t2, xv, yv, o);
#pragma unroll
  for (int i = 0; i < 8; ++i) orow[16 + i] = o[i];
  sample_level_direct<512>(t3, xv, yv, o);
#pragma unroll
  for (int i = 0; i < 8; ++i) orow[24 + i] = o[i];
  sample_level_direct<1024>(t4, xv, yv, o);
#pragma unroll
  for (int i = 0; i < 8; ++i) orow[32 + i] = o[i];
}

extern "C" void kernel_launch(void* const* d_in, const int* in_sizes, int n_in,
                              void* d_out, int out_size, void* d_ws, size_t ws_size,
                              hipStream_t stream) {
  const float* x = (const float*)d_in[0];
  const float* y = (const float*)d_in[1];
  const float* tabs[5] = {(const float*)d_in[2], (const float*)d_in[3],
                          (const float*)d_in[4], (const float*)d_in[5],
                          (const float*)d_in[6]};
  float* out = (float*)d_out;
  const int P = in_sizes[0];

  const size_t offs[5] = {0, 8192, 40960, 172032, 696320};
  const size_t total_px = 2793472;
  size_t need = WS_TAB + total_px * sizeof(uint2);

  if (ws_size >= need && P <= 1000448) {
    float* deq = (float*)d_ws;
    float* inv = (float*)((char*)d_ws + 32);
    unsigned* partials = (unsigned*)((char*)d_ws + WS_PART);
    unsigned* cursor = (unsigned*)((char*)d_ws + WS_CURS);
    unsigned* ovf_cnt = (unsigned*)((char*)d_ws + WS_OVFC);
    int* ovf = (int*)((char*)d_ws + WS_OVF);
    int* perm = (int*)((char*)d_ws + WS_PERM);
    float2* sxy = (float2*)((char*)d_ws + WS_SXY);
    uint2* tb = (uint2*)((char*)d_ws + WS_TAB);

    // zero cursor[4096] and ovf_cnt in one memset (contiguous region)
    (void)hipMemsetAsync((char*)d_ws + WS_CURS, 0, (WS_OVFC - WS_CURS) + 4,
                         stream);
    absmax_scatter_kernel<<<5456 + 2048, 256, 0, stream>>>(
        tabs[0], tabs[1], tabs[2], tabs[3], tabs[4], partials, x, y, P, cursor,
        ovf_cnt, ovf, perm, sxy);
    finalize_scales_kernel<<<1, 256, 0, stream>>>(partials, deq, inv);
    quant_kernel<<<10912, 256, 0, stream>>>(
        tabs[0], tabs[1], tabs[2], tabs[3], tabs[4], tb, inv);
    sample_tile_kernel<<<NGRP + 32, 256, 0, stream>>>(
        sxy, perm, cursor, ovf_cnt, ovf, x, y, tb + offs[0], tb + offs[1],
        tb + offs[2], tb + offs[3], tb + offs[4], deq, out, P);
  } else {
    sample_kernel_direct<<<(P + 255) / 256, 256, 0, stream>>>(
        x, y, tabs[0], tabs[1], tabs[2], tabs[3], tabs[4], out, P);
  }
}